// Round 2
// baseline (5034.982 us; speedup 1.0000x reference)
//
#include <hip/hip_runtime.h>
#include <math.h>

// ---- row strides (dwords), all odd-multiples-of-4 for bank spread + b128 align
#define SV 100   // 96-float vector buffers
#define SD 68    // 64-float scalar buffer
#define SE 132   // 128-float scalar buffer
#define SG 36    // 32-float gate buffers
#define SN 164   // 160-float node cat buffer

// ---------------- edge LDS layout (dword offsets) ----------------
#define EA    0                    // 64 x SV : v -> vi -> ev_lin -> vi_o
#define EB    (EA + 64*SV)         // 64 x SV : ev -> nv_g -> y_v -> ov_pre
#define EDD   (EB + 64*SV)         // 64 x SD : es -> ses
#define EEB   (EDD + 64*SD)        // 64 x SE : cat(norm|s) -> d -> ns_g -> y_s -> os
#define ESM   (EEB + 64*SE)        // 64 x SG : gate -> e2n -> norm_o
#define ESM2  (ESM + 64*SG)        // 64 x SG : n2e -> gate_o
#define ECUT  (ESM2 + 64*SG)       // 64 floats
#define EIDXO (ECUT + 64)          // 64 ints
#define EDGE_LDS_FLOATS (EIDXO + 64)
#define EDGE_LDS_BYTES  (EDGE_LDS_FLOATS*4)

// ---------------- node LDS layout ----------------
#define NA   0                     // 64 x SV : v -> vi
#define NEB  (NA + 64*SV)          // 64 x SN : cat = [norm(32) | s(128)]
#define NDD  (NEB + 64*SN)         // 64 x SE : out_s
#define NSMB (NDD + 64*SE)         // 64 x SG : gate
#define NODE_LDS_FLOATS (NSMB + 64*SG)
#define NODE_LDS_BYTES  (NODE_LDS_FLOATS*4)

__device__ __forceinline__ float sigmoidf_(float z) {
    return 1.0f / (1.0f + expf(-z));
}

// vector GEMM: out[j][c] = sum_i W[(w4+j)*32+i] * In[e][i*3+c], In read as float4
__device__ __forceinline__ void vgemm32(const float* Lin, const float* __restrict__ Wp,
                                        float a[4][3]) {
    const float4* p = (const float4*)Lin;
#pragma unroll
    for (int j=0;j<4;j++){ a[j][0]=0.f; a[j][1]=0.f; a[j][2]=0.f; }
#pragma unroll 2
    for (int c8=0;c8<8;c8++){
        float4 q0=p[c8*3+0], q1=p[c8*3+1], q2=p[c8*3+2];
        float x[12]={q0.x,q0.y,q0.z,q0.w,q1.x,q1.y,q1.z,q1.w,q2.x,q2.y,q2.z,q2.w};
#pragma unroll
        for (int j=0;j<4;j++){
#pragma unroll
            for (int ii=0;ii<4;ii++){
                float wv = Wp[j*32 + c8*4 + ii];
                a[j][0]=fmaf(wv,x[ii*3+0],a[j][0]);
                a[j][1]=fmaf(wv,x[ii*3+1],a[j][1]);
                a[j][2]=fmaf(wv,x[ii*3+2],a[j][2]);
            }
        }
    }
}

// scalar GEMM accumulate: a[j] += sum_k W[j*KW + k] * x[k], x from float4* p
template<int K4, int J, int KW>
__device__ __forceinline__ void sgemm_acc(const float4* p, const float* __restrict__ Wp,
                                          float* a) {
#pragma unroll 2
    for (int k4=0;k4<K4;k4++){
        float4 x = p[k4];
#pragma unroll
        for (int j=0;j<J;j++){
            a[j]=fmaf(Wp[j*KW+k4*4+0],x.x,a[j]);
            a[j]=fmaf(Wp[j*KW+k4*4+1],x.y,a[j]);
            a[j]=fmaf(Wp[j*KW+k4*4+2],x.z,a[j]);
            a[j]=fmaf(Wp[j*KW+k4*4+3],x.w,a[j]);
        }
    }
}

__device__ __forceinline__ void pack12(const float a[4][3], float4* dst) {
    dst[0] = make_float4(a[0][0],a[0][1],a[0][2],a[1][0]);
    dst[1] = make_float4(a[1][1],a[1][2],a[2][0],a[2][1]);
    dst[2] = make_float4(a[2][2],a[3][0],a[3][1],a[3][2]);
}

// =====================================================================
// Node kernel
// =====================================================================
__global__ __launch_bounds__(512)
void node_kernel(const float* __restrict__ node_s, const float* __restrict__ node_v,
                 const float* __restrict__ Wv1, const float* __restrict__ Wv2,
                 const float* __restrict__ Ws,  const float* __restrict__ Wg,
                 const float* __restrict__ bg,
                 float* __restrict__ ns_ws, float* __restrict__ nv_ws, int N)
{
    extern __shared__ float L[];
    const int t = threadIdx.x;
    const int e = t & 63;
    const int w = __builtin_amdgcn_readfirstlane(t >> 6);
    const size_t n0 = (size_t)blockIdx.x * 64;
    const int valid = (int)min((size_t)64, (size_t)N - n0);

    // ---- stage 0: v -> NA[e][0..95], s -> NEB[e][32..159]
    {
        int eL = t>>3, q = t&7;
        size_t row = n0 + (size_t)eL; if (row >= (size_t)N) row = (size_t)N-1;
        const float4* gv = (const float4*)(node_v + row*96);
        float4* av = (float4*)&L[NA + eL*SV];
#pragma unroll
        for (int r=0;r<3;r++) av[q+8*r] = gv[q+8*r];
        const float4* gs = (const float4*)(node_s + row*128);
        float4* cs = (float4*)&L[NEB + eL*SN + 32];
#pragma unroll
        for (int r=0;r<4;r++) cs[q+8*r] = gs[q+8*r];
    }
    __syncthreads();

    // ---- G1: vi = Wv1 @ v (in place in NA)
    {
        float a[4][3];
        vgemm32(&L[NA + e*SV], Wv1 + (w*4)*32, a);
        __syncthreads();
        float4 pk[3]; pack12(a, pk);
        float4* dst = (float4*)&L[NA + e*SV];
#pragma unroll
        for (int m=0;m<3;m++) dst[3*w+m] = pk[m];
    }
    __syncthreads();

    // ---- norm -> NEB[e][0..31]
    for (int idx=t; idx<2048; idx+=512){
        int ee=idx>>5, h=idx&31;
        float x0=L[NA+ee*SV+3*h+0], x1=L[NA+ee*SV+3*h+1], x2=L[NA+ee*SV+3*h+2];
        L[NEB+ee*SN+h]=sqrtf(x0*x0+x1*x1+x2*x2);
    }
    __syncthreads();

    // ---- G2: out_s = Ws @ cat (K=160) -> NDD + global
    {
        float a[16];
#pragma unroll
        for (int j=0;j<16;j++) a[j]=0.f;
        sgemm_acc<40,16,160>((const float4*)&L[NEB + e*SN], Ws + (size_t)(w*16)*160, a);
        float4* dd = (float4*)&L[NDD + e*SE];
#pragma unroll
        for (int q=0;q<4;q++) dd[w*4+q] = make_float4(a[q*4+0],a[q*4+1],a[q*4+2],a[q*4+3]);
        if (e < valid){
            float4* po = (float4*)(ns_ws + (n0+(size_t)e)*128 + w*16);
#pragma unroll
            for (int q=0;q<4;q++) po[q] = make_float4(a[q*4+0],a[q*4+1],a[q*4+2],a[q*4+3]);
        }
    }
    __syncthreads();

    // ---- G3: gate = sigmoid(Wg @ out_s + bg) -> NSMB
    {
        float a[4]={0.f,0.f,0.f,0.f};
        sgemm_acc<32,4,128>((const float4*)&L[NDD + e*SE], Wg + (w*4)*128, a);
        float4 g4 = make_float4(sigmoidf_(a[0]+bg[w*4+0]), sigmoidf_(a[1]+bg[w*4+1]),
                                sigmoidf_(a[2]+bg[w*4+2]), sigmoidf_(a[3]+bg[w*4+3]));
        ((float4*)&L[NSMB + e*SG])[w] = g4;
    }
    __syncthreads();

    // ---- G4: out_v = gate * (Wv2 @ vi) -> global
    {
        float a[4][3];
        vgemm32(&L[NA + e*SV], Wv2 + (w*4)*32, a);
        if (e < valid){
#pragma unroll
            for (int j=0;j<4;j++){
                float g = L[NSMB + e*SG + w*4 + j];
                a[j][0]*=g; a[j][1]*=g; a[j][2]*=g;
            }
            float4 pk[3]; pack12(a, pk);
            float4* pv = (float4*)(nv_ws + (n0+(size_t)e)*96 + w*12);
#pragma unroll
            for (int m=0;m<3;m++) pv[m] = pk[m];
        }
    }
}

// =====================================================================
// Edge kernel
// =====================================================================
__global__ __launch_bounds__(512)
void edge_kernel(const float* __restrict__ edge_s_g, const float* __restrict__ edge_v_g,
                 const int* __restrict__ eidx_g, const float* __restrict__ dist_g,
                 const float* __restrict__ eWv1, const float* __restrict__ eWv2,
                 const float* __restrict__ eWs,  const float* __restrict__ eWg,
                 const float* __restrict__ ebg,  const float* __restrict__ eWd,
                 const float* __restrict__ scaW, const float* __restrict__ scab,
                 const float* __restrict__ e2nW, const float* __restrict__ e2nb,
                 const float* __restrict__ n2eW, const float* __restrict__ n2eb,
                 const float* __restrict__ evnW, const float* __restrict__ evnb,
                 const float* __restrict__ oWv1, const float* __restrict__ oWv2,
                 const float* __restrict__ oWs,  const float* __restrict__ oWg,
                 const float* __restrict__ obg,
                 const float* __restrict__ ns_ws, const float* __restrict__ nv_ws,
                 float* __restrict__ outS, float* __restrict__ outV, int E)
{
    extern __shared__ float L[];
    int* LI = (int*)&L[EIDXO];
    const int t = threadIdx.x;
    const int e = t & 63;
    const int w = __builtin_amdgcn_readfirstlane(t >> 6);
    const size_t e0 = (size_t)blockIdx.x * 64;
    const int valid = (int)min((size_t)64, (size_t)E - e0);
    const float PI_F = 3.14159265358979323846f;

    // ---- stage 0
    {
        int eL = t>>3, q = t&7;
        size_t row = e0 + (size_t)eL; if (row >= (size_t)E) row = (size_t)E-1;
        const float4* gv = (const float4*)(edge_v_g + row*96);
        float4* av = (float4*)&L[EA + eL*SV];
#pragma unroll
        for (int r=0;r<3;r++) av[q+8*r] = gv[q+8*r];
        const float4* gs = (const float4*)(edge_s_g + row*64);
        float4* cs = (float4*)&L[EEB + eL*SE + 32];
#pragma unroll
        for (int r=0;r<2;r++) cs[q+8*r] = gs[q+8*r];
    }
    if (t < 64) {
        size_t row = e0 + (size_t)t; if (row >= (size_t)E) row = (size_t)E-1;
        LI[t] = eidx_g[row];
        float dd = dist_g[row];
        float c = 0.5f*(cosf(dd * (PI_F/10.0f)) + 1.0f);
        c = (dd >= 0.0f && dd <= 10.0f) ? c : 0.0f;
        L[ECUT + t] = c;
    }
    __syncthreads();

    // ---- G1: vi = eWv1 @ v (in place in A)
    {
        float a[4][3];
        vgemm32(&L[EA + e*SV], eWv1 + (w*4)*32, a);
        __syncthreads();
        float4 pk[3]; pack12(a, pk);
        float4* dst = (float4*)&L[EA + e*SV];
#pragma unroll
        for (int m=0;m<3;m++) dst[3*w+m] = pk[m];
    }
    __syncthreads();

    // ---- norm -> E rows 0..31
    for (int idx=t; idx<2048; idx+=512){
        int ee=idx>>5, h=idx&31;
        float x0=L[EA+ee*SV+3*h+0], x1=L[EA+ee*SV+3*h+1], x2=L[EA+ee*SV+3*h+2];
        L[EEB+ee*SE+h]=sqrtf(x0*x0+x1*x1+x2*x2);
    }
    __syncthreads();

    // ---- G2: es = eWs @ cat (K=96) -> D
    {
        float a[8];
#pragma unroll
        for (int j=0;j<8;j++) a[j]=0.f;
        sgemm_acc<24,8,96>((const float4*)&L[EEB + e*SE], eWs + (w*8)*96, a);
        float4* dd = (float4*)&L[EDD + e*SD];
#pragma unroll
        for (int q=0;q<2;q++) dd[w*2+q] = make_float4(a[q*4+0],a[q*4+1],a[q*4+2],a[q*4+3]);
    }
    __syncthreads();

    // ---- G3: gate = sigmoid(eWg @ es + ebg) -> SM
    {
        float a[4]={0.f,0.f,0.f,0.f};
        sgemm_acc<16,4,64>((const float4*)&L[EDD + e*SD], eWg + (w*4)*64, a);
        float4 g4 = make_float4(sigmoidf_(a[0]+ebg[w*4+0]), sigmoidf_(a[1]+ebg[w*4+1]),
                                sigmoidf_(a[2]+ebg[w*4+2]), sigmoidf_(a[3]+ebg[w*4+3]));
        ((float4*)&L[ESM + e*SG])[w] = g4;
    }
    __syncthreads();

    // ---- G4: ev = gate * (eWv2 @ vi) -> B
    {
        float a[4][3];
        vgemm32(&L[EA + e*SV], eWv2 + (w*4)*32, a);
#pragma unroll
        for (int j=0;j<4;j++){
            float g = L[ESM + e*SG + w*4 + j];
            a[j][0]*=g; a[j][1]*=g; a[j][2]*=g;
        }
        float4 pk[3]; pack12(a, pk);
        float4* dst = (float4*)&L[EB + e*SV];
#pragma unroll
        for (int m=0;m<3;m++) dst[3*w+m] = pk[m];
    }
    __syncthreads();

    // ---- G5: d = eWd @ ev -> E rows 0..95
    {
        float a[4][3];
        vgemm32(&L[EB + e*SV], eWd + (w*4)*32, a);
        float4 pk[3]; pack12(a, pk);
        float4* dst = (float4*)&L[EEB + e*SE];
#pragma unroll
        for (int m=0;m<3;m++) dst[3*w+m] = pk[m];
    }
    __syncthreads();

    // ---- VNLeakyReLU (B in place), leaky on es (D in place)
    for (int idx=t; idx<2048; idx+=512){
        int ee=idx>>5, o=idx&31;
        float x0=L[EB+ee*SV+3*o+0], x1=L[EB+ee*SV+3*o+1], x2=L[EB+ee*SV+3*o+2];
        float d0=L[EEB+ee*SE+3*o+0], d1=L[EEB+ee*SE+3*o+1], d2=L[EEB+ee*SE+3*o+2];
        float dot=x0*d0+x1*d1+x2*d2;
        float dn =d0*d0+d1*d1+d2*d2;
        float s_ = dot/(dn + 1e-6f);
        float y0,y1,y2;
        if (dot >= 0.f){ y0=x0; y1=x1; y2=x2; }
        else { y0=x0-s_*d0; y1=x1-s_*d1; y2=x2-s_*d2; }
        L[EB+ee*SV+3*o+0]=0.01f*x0+0.99f*y0;
        L[EB+ee*SV+3*o+1]=0.01f*x1+0.99f*y1;
        L[EB+ee*SV+3*o+2]=0.01f*x2+0.99f*y2;
    }
    for (int idx=t; idx<4096; idx+=512){
        int ee=idx>>6, k=idx&63;
        float x=L[EDD+ee*SD+k];
        L[EDD+ee*SD+k]=(x>=0.f)? x : 0.01f*x;
    }
    __syncthreads();

    // ---- G6: ev_lin = evnW @ ev + evnb -> A
    {
        float a[4][3];
        vgemm32(&L[EB + e*SV], evnW + (w*4)*32, a);
#pragma unroll
        for (int j=0;j<4;j++){
            float b = evnb[w*4+j];
            a[j][0]+=b; a[j][1]+=b; a[j][2]+=b;
        }
        float4 pk[3]; pack12(a, pk);
        float4* dst = (float4*)&L[EA + e*SV];
#pragma unroll
        for (int m=0;m<3;m++) dst[3*w+m] = pk[m];
    }
    __syncthreads();

    // ---- gather: ns_g -> E[0..127], nv_g -> B
    {
        int eL = t>>3, q = t&7;
        size_t j = (size_t)LI[eL];
        const float4* np_ = (const float4*)(ns_ws + j*128);
        float4* de = (float4*)&L[EEB + eL*SE];
#pragma unroll
        for (int r=0;r<4;r++) de[q+8*r] = np_[q+8*r];
        const float4* vp_ = (const float4*)(nv_ws + j*96);
        float4* db = (float4*)&L[EB + eL*SV];
#pragma unroll
        for (int r=0;r<3;r++) db[q+8*r] = vp_[q+8*r];
    }
    __syncthreads();

    // ---- G8: e2n -> SM ; G9: n2e -> SM2
    {
        float a[4]={0.f,0.f,0.f,0.f};
        sgemm_acc<16,4,64>((const float4*)&L[EDD + e*SD], e2nW + (w*4)*64, a);
        ((float4*)&L[ESM + e*SG])[w] = make_float4(a[0]+e2nb[w*4+0], a[1]+e2nb[w*4+1],
                                                   a[2]+e2nb[w*4+2], a[3]+e2nb[w*4+3]);
        float b[4]={0.f,0.f,0.f,0.f};
        sgemm_acc<32,4,128>((const float4*)&L[EEB + e*SE], n2eW + (w*4)*128, b);
        ((float4*)&L[ESM2 + e*SG])[w] = make_float4(b[0]+n2eb[w*4+0], b[1]+n2eb[w*4+1],
                                                    b[2]+n2eb[w*4+2], b[3]+n2eb[w*4+3]);
    }
    __syncthreads();

    // ---- y_v = e2n*nv_g + n2e*ev_lin -> B in place
    for (int idx=t; idx<2048; idx+=512){
        int ee=idx>>5, o=idx&31;
        float g1=L[ESM+ee*SG+o], g2=L[ESM2+ee*SG+o];
#pragma unroll
        for (int c=0;c<3;c++){
            L[EB+ee*SV+3*o+c] = g1*L[EB+ee*SV+3*o+c] + g2*L[EA+ee*SV+3*o+c];
        }
    }
    __syncthreads();

    // ---- G7: y_s = ns_g * (scaW @ ses + scab) -> E in place (own slots)
    {
        float a[16];
#pragma unroll
        for (int j=0;j<16;j++) a[j]=0.f;
        sgemm_acc<16,16,64>((const float4*)&L[EDD + e*SD], scaW + (size_t)(w*16)*64, a);
        float4* pe = (float4*)&L[EEB + e*SE];
#pragma unroll
        for (int q=0;q<4;q++){
            float4 ns4 = pe[w*4+q];
            int o0 = w*16+q*4;
            pe[w*4+q] = make_float4(ns4.x*(a[q*4+0]+scab[o0+0]), ns4.y*(a[q*4+1]+scab[o0+1]),
                                    ns4.z*(a[q*4+2]+scab[o0+2]), ns4.w*(a[q*4+3]+scab[o0+3]));
        }
    }
    __syncthreads();

    // ---- G10: vi_o = oWv1 @ y_v -> A
    {
        float a[4][3];
        vgemm32(&L[EB + e*SV], oWv1 + (w*4)*32, a);
        float4 pk[3]; pack12(a, pk);
        float4* dst = (float4*)&L[EA + e*SV];
#pragma unroll
        for (int m=0;m<3;m++) dst[3*w+m] = pk[m];
    }
    __syncthreads();

    // ---- norm_o -> SM
    for (int idx=t; idx<2048; idx+=512){
        int ee=idx>>5, h=idx&31;
        float x0=L[EA+ee*SV+3*h+0], x1=L[EA+ee*SV+3*h+1], x2=L[EA+ee*SV+3*h+2];
        L[ESM+ee*SG+h]=sqrtf(x0*x0+x1*x1+x2*x2);
    }
    __syncthreads();

    // ---- G13: ov_pre = oWv2 @ vi_o -> B
    {
        float a[4][3];
        vgemm32(&L[EA + e*SV], oWv2 + (w*4)*32, a);
        float4 pk[3]; pack12(a, pk);
        float4* dst = (float4*)&L[EB + e*SV];
#pragma unroll
        for (int m=0;m<3;m++) dst[3*w+m] = pk[m];
    }
    __syncthreads();

    // ---- G11: os = oWs @ [norm_o(32) ; y_s(128)] -> E in place (regs+barrier)
    {
        float a[16];
#pragma unroll
        for (int j=0;j<16;j++) a[j]=0.f;
        sgemm_acc<8,16,160>((const float4*)&L[ESM + e*SG], oWs + (size_t)(w*16)*160, a);
        sgemm_acc<32,16,160>((const float4*)&L[EEB + e*SE], oWs + (size_t)(w*16)*160 + 32, a);
        __syncthreads();
        float4* pe = (float4*)&L[EEB + e*SE];
#pragma unroll
        for (int q=0;q<4;q++) pe[w*4+q] = make_float4(a[q*4+0],a[q*4+1],a[q*4+2],a[q*4+3]);
    }
    __syncthreads();

    // ---- G12: gate_o = sigmoid(oWg @ os + obg) -> SM2
    {
        float a[4]={0.f,0.f,0.f,0.f};
        sgemm_acc<32,4,128>((const float4*)&L[EEB + e*SE], oWg + (w*4)*128, a);
        ((float4*)&L[ESM2 + e*SG])[w] = make_float4(sigmoidf_(a[0]+obg[w*4+0]), sigmoidf_(a[1]+obg[w*4+1]),
                                                    sigmoidf_(a[2]+obg[w*4+2]), sigmoidf_(a[3]+obg[w*4+3]));
    }
    __syncthreads();

    // ---- outputs with cutoff
    if (e < valid) {
        float c = L[ECUT + e];
        const float4* pe = (const float4*)&L[EEB + e*SE];
        float4* po = (float4*)(outS + (e0+(size_t)e)*128 + w*16);
#pragma unroll
        for (int q=0;q<4;q++){
            float4 v4 = pe[w*4+q];
            po[q] = make_float4(v4.x*c, v4.y*c, v4.z*c, v4.w*c);
        }
        float a[4][3];
#pragma unroll
        for (int j=0;j<4;j++){
            int o=w*4+j;
            float g=L[ESM2+e*SG+o]*c;
            a[j][0]=g*L[EB+e*SV+3*o+0];
            a[j][1]=g*L[EB+e*SV+3*o+1];
            a[j][2]=g*L[EB+e*SV+3*o+2];
        }
        float4 pk[3]; pack12(a, pk);
        float4* pv = (float4*)(outV + (e0+(size_t)e)*96 + w*12);
#pragma unroll
        for (int m=0;m<3;m++) pv[m] = pk[m];
    }
}

// =====================================================================
extern "C" void kernel_launch(void* const* d_in, const int* in_sizes, int n_in,
                              void* d_out, int out_size, void* d_ws, size_t ws_size,
                              hipStream_t stream) {
    const float* node_s = (const float*)d_in[0];
    const float* node_v = (const float*)d_in[1];
    const float* edge_s = (const float*)d_in[2];
    const float* edge_v = (const float*)d_in[3];
    const int*   eidx   = (const int*)d_in[4];
    const float* dist   = (const float*)d_in[5];
    const float* nWv1=(const float*)d_in[6],  *nWv2=(const float*)d_in[7];
    const float* nWs =(const float*)d_in[8],  *nWg =(const float*)d_in[9],  *nbg=(const float*)d_in[10];
    const float* eWv1=(const float*)d_in[11], *eWv2=(const float*)d_in[12];
    const float* eWs =(const float*)d_in[13], *eWg =(const float*)d_in[14], *ebg=(const float*)d_in[15];
    const float* eWd =(const float*)d_in[16];
    const float* scaW=(const float*)d_in[17], *scab=(const float*)d_in[18];
    const float* e2nW=(const float*)d_in[19], *e2nb=(const float*)d_in[20];
    const float* n2eW=(const float*)d_in[21], *n2eb=(const float*)d_in[22];
    const float* evnW=(const float*)d_in[23], *evnb=(const float*)d_in[24];
    const float* oWv1=(const float*)d_in[25], *oWv2=(const float*)d_in[26];
    const float* oWs =(const float*)d_in[27], *oWg =(const float*)d_in[28], *obg=(const float*)d_in[29];

    const int N = in_sizes[0] / 128;
    const int E = in_sizes[2] / 64;

    float* ns_ws = (float*)d_ws;
    float* nv_ws = ns_ws + (size_t)N*128;
    float* outS  = (float*)d_out;
    float* outV  = outS + (size_t)E*128;

    hipFuncSetAttribute((const void*)node_kernel, hipFuncAttributeMaxDynamicSharedMemorySize, NODE_LDS_BYTES);
    hipFuncSetAttribute((const void*)edge_kernel, hipFuncAttributeMaxDynamicSharedMemorySize, EDGE_LDS_BYTES);

    const int nb = (N + 63) / 64;
    node_kernel<<<nb, 512, NODE_LDS_BYTES, stream>>>(node_s, node_v, nWv1, nWv2, nWs, nWg, nbg,
                                                     ns_ws, nv_ws, N);

    const int eb = (E + 63) / 64;
    edge_kernel<<<eb, 512, EDGE_LDS_BYTES, stream>>>(edge_s, edge_v, eidx, dist,
                                                     eWv1, eWv2, eWs, eWg, ebg, eWd,
                                                     scaW, scab, e2nW, e2nb, n2eW, n2eb, evnW, evnb,
                                                     oWv1, oWv2, oWs, oWg, obg,
                                                     ns_ws, nv_ws, outS, outV, E);
}

// Round 3
// 2745.921 us; speedup vs baseline: 1.8336x; 1.8336x over previous
//
#include <hip/hip_runtime.h>
#include <math.h>

typedef unsigned int uint;
typedef unsigned short ushort;
typedef short bf16x8 __attribute__((ext_vector_type(8)));
typedef float f32x4 __attribute__((ext_vector_type(4)));

__device__ __forceinline__ float sigmoidf_(float z) {
    return 1.0f / (1.0f + expf(-z));
}

__device__ __forceinline__ uint cvt2bf(float a, float b){
    uint r; asm("v_cvt_pk_bf16_f32 %0, %1, %2" : "=v"(r) : "v"(a), "v"(b)); return r;
}
__device__ __forceinline__ ushort f2bf(float a){ return (ushort)(cvt2bf(a, 0.f) & 0xffffu); }
__device__ __forceinline__ float bf2f(ushort u){ return __uint_as_float(((uint)u)<<16); }

union BFU { bf16x8 v; uint u[4]; ushort s[8]; };

// ============================ NODE KERNEL (unchanged from R2) ============================
#define SV 100
#define SE 132
#define SG 36
#define SN 164
#define NA   0
#define NEB  (NA + 64*SV)
#define NDD  (NEB + 64*SN)
#define NSMB (NDD + 64*SE)
#define NODE_LDS_FLOATS (NSMB + 64*SG)
#define NODE_LDS_BYTES  (NODE_LDS_FLOATS*4)

__device__ __forceinline__ void vgemm32(const float* Lin, const float* __restrict__ Wp,
                                        float a[4][3]) {
    const float4* p = (const float4*)Lin;
#pragma unroll
    for (int j=0;j<4;j++){ a[j][0]=0.f; a[j][1]=0.f; a[j][2]=0.f; }
#pragma unroll 2
    for (int c8=0;c8<8;c8++){
        float4 q0=p[c8*3+0], q1=p[c8*3+1], q2=p[c8*3+2];
        float x[12]={q0.x,q0.y,q0.z,q0.w,q1.x,q1.y,q1.z,q1.w,q2.x,q2.y,q2.z,q2.w};
#pragma unroll
        for (int j=0;j<4;j++){
#pragma unroll
            for (int ii=0;ii<4;ii++){
                float wv = Wp[j*32 + c8*4 + ii];
                a[j][0]=fmaf(wv,x[ii*3+0],a[j][0]);
                a[j][1]=fmaf(wv,x[ii*3+1],a[j][1]);
                a[j][2]=fmaf(wv,x[ii*3+2],a[j][2]);
            }
        }
    }
}

template<int K4, int J, int KW>
__device__ __forceinline__ void sgemm_acc(const float4* p, const float* __restrict__ Wp,
                                          float* a) {
#pragma unroll 2
    for (int k4=0;k4<K4;k4++){
        float4 x = p[k4];
#pragma unroll
        for (int j=0;j<J;j++){
            a[j]=fmaf(Wp[j*KW+k4*4+0],x.x,a[j]);
            a[j]=fmaf(Wp[j*KW+k4*4+1],x.y,a[j]);
            a[j]=fmaf(Wp[j*KW+k4*4+2],x.z,a[j]);
            a[j]=fmaf(Wp[j*KW+k4*4+3],x.w,a[j]);
        }
    }
}

__device__ __forceinline__ void pack12(const float a[4][3], float4* dst) {
    dst[0] = make_float4(a[0][0],a[0][1],a[0][2],a[1][0]);
    dst[1] = make_float4(a[1][1],a[1][2],a[2][0],a[2][1]);
    dst[2] = make_float4(a[2][2],a[3][0],a[3][1],a[3][2]);
}

__global__ __launch_bounds__(512)
void node_kernel(const float* __restrict__ node_s, const float* __restrict__ node_v,
                 const float* __restrict__ Wv1, const float* __restrict__ Wv2,
                 const float* __restrict__ Ws,  const float* __restrict__ Wg,
                 const float* __restrict__ bg,
                 float* __restrict__ ns_ws, float* __restrict__ nv_ws, int N)
{
    extern __shared__ float L[];
    const int t = threadIdx.x;
    const int e = t & 63;
    const int w = __builtin_amdgcn_readfirstlane(t >> 6);
    const size_t n0 = (size_t)blockIdx.x * 64;
    const int valid = (int)min((size_t)64, (size_t)N - n0);

    {
        int eL = t>>3, q = t&7;
        size_t row = n0 + (size_t)eL; if (row >= (size_t)N) row = (size_t)N-1;
        const float4* gv = (const float4*)(node_v + row*96);
        float4* av = (float4*)&L[NA + eL*SV];
#pragma unroll
        for (int r=0;r<3;r++) av[q+8*r] = gv[q+8*r];
        const float4* gs = (const float4*)(node_s + row*128);
        float4* cs = (float4*)&L[NEB + eL*SN + 32];
#pragma unroll
        for (int r=0;r<4;r++) cs[q+8*r] = gs[q+8*r];
    }
    __syncthreads();

    {
        float a[4][3];
        vgemm32(&L[NA + e*SV], Wv1 + (w*4)*32, a);
        __syncthreads();
        float4 pk[3]; pack12(a, pk);
        float4* dst = (float4*)&L[NA + e*SV];
#pragma unroll
        for (int m=0;m<3;m++) dst[3*w+m] = pk[m];
    }
    __syncthreads();

    for (int idx=t; idx<2048; idx+=512){
        int ee=idx>>5, h=idx&31;
        float x0=L[NA+ee*SV+3*h+0], x1=L[NA+ee*SV+3*h+1], x2=L[NA+ee*SV+3*h+2];
        L[NEB+ee*SN+h]=sqrtf(x0*x0+x1*x1+x2*x2);
    }
    __syncthreads();

    {
        float a[16];
#pragma unroll
        for (int j=0;j<16;j++) a[j]=0.f;
        sgemm_acc<40,16,160>((const float4*)&L[NEB + e*SN], Ws + (size_t)(w*16)*160, a);
        float4* dd = (float4*)&L[NDD + e*SE];
#pragma unroll
        for (int q=0;q<4;q++) dd[w*4+q] = make_float4(a[q*4+0],a[q*4+1],a[q*4+2],a[q*4+3]);
        if (e < valid){
            float4* po = (float4*)(ns_ws + (n0+(size_t)e)*128 + w*16);
#pragma unroll
            for (int q=0;q<4;q++) po[q] = make_float4(a[q*4+0],a[q*4+1],a[q*4+2],a[q*4+3]);
        }
    }
    __syncthreads();

    {
        float a[4]={0.f,0.f,0.f,0.f};
        sgemm_acc<32,4,128>((const float4*)&L[NDD + e*SE], Wg + (w*4)*128, a);
        float4 g4 = make_float4(sigmoidf_(a[0]+bg[w*4+0]), sigmoidf_(a[1]+bg[w*4+1]),
                                sigmoidf_(a[2]+bg[w*4+2]), sigmoidf_(a[3]+bg[w*4+3]));
        ((float4*)&L[NSMB + e*SG])[w] = g4;
    }
    __syncthreads();

    {
        float a[4][3];
        vgemm32(&L[NA + e*SV], Wv2 + (w*4)*32, a);
        if (e < valid){
#pragma unroll
            for (int j=0;j<4;j++){
                float g = L[NSMB + e*SG + w*4 + j];
                a[j][0]*=g; a[j][1]*=g; a[j][2]*=g;
            }
            float4 pk[3]; pack12(a, pk);
            float4* pv = (float4*)(nv_ws + (n0+(size_t)e)*96 + w*12);
#pragma unroll
            for (int m=0;m<3;m++) pv[m] = pk[m];
        }
    }
}

// ============================ EDGE KERNEL (MFMA rewrite) ============================
// LDS byte layout
#define X_EA    0                  // f32 [64][96] quad-xor
#define X_EB    24576              // f32 [64][96] quad-xor
#define X_ESM   49152              // f32 [64][36]
#define X_ESM2  58368              // f32 [64][36]
#define X_EDD   67584              // bf16 [64][72]  (es / ses)
#define X_EEB   76800              // bf16 [64][136] (cat -> d -> ns_g -> y_s)
#define X_BIAS  94208              // f32 [256]
#define X_ECUT  95232              // f32 [64]
#define X_EIDX  95488              // int [64]
#define X_AR    95744              // arena bf16 (phase1/2) / os f32
#define EDGE_LDS_BYTES 147456
// arena ushort offsets
#define AW_EWS  0        // eWs  [64][104]
#define AW_EWG  6656     // eWg  [32][72]
#define AW_E2N  8960     // e2nW [32][72]
#define AW_N2E  11264    // n2eW [32][136]
#define AW_SCA  15616    // scaW [128][72]
#define AW_OWS  0        // oWs  [128][168]
#define AW_OWG  21504    // oWg  [32][136]

__device__ __forceinline__ float ld_swz(const float* rb, int e7, int d){
    return rb[(((d>>2)^e7)<<2) + (d&3)];
}
__device__ __forceinline__ void st_swz(float* rb, int e7, int d, float v){
    rb[(((d>>2)^e7)<<2) + (d&3)] = v;
}

__device__ __forceinline__ void vgemm32s(const float* rp, int e7, const float* __restrict__ Wp,
                                         float a[4][3]) {
    const float4* p = (const float4*)rp;
#pragma unroll
    for (int j=0;j<4;j++){ a[j][0]=0.f; a[j][1]=0.f; a[j][2]=0.f; }
#pragma unroll 2
    for (int c8=0;c8<8;c8++){
        float4 q0=p[(c8*3+0)^e7], q1=p[(c8*3+1)^e7], q2=p[(c8*3+2)^e7];
        float x[12]={q0.x,q0.y,q0.z,q0.w,q1.x,q1.y,q1.z,q1.w,q2.x,q2.y,q2.z,q2.w};
#pragma unroll
        for (int j=0;j<4;j++){
#pragma unroll
            for (int ii=0;ii<4;ii++){
                float wv = Wp[j*32 + c8*4 + ii];
                a[j][0]=fmaf(wv,x[ii*3+0],a[j][0]);
                a[j][1]=fmaf(wv,x[ii*3+1],a[j][1]);
                a[j][2]=fmaf(wv,x[ii*3+2],a[j][2]);
            }
        }
    }
}

__device__ __forceinline__ void store_pack12_swz(float* rp, int e7, int w, const float a[4][3]){
    float4* p = (float4*)rp;
    p[(3*w+0)^e7] = make_float4(a[0][0],a[0][1],a[0][2],a[1][0]);
    p[(3*w+1)^e7] = make_float4(a[1][1],a[1][2],a[2][0],a[2][1]);
    p[(3*w+2)^e7] = make_float4(a[2][2],a[3][0],a[3][1],a[3][2]);
}

// stage f32 global weights -> bf16 LDS [J][Kp]
template<int K, int Kp>
__device__ __forceinline__ void stageW(const float* __restrict__ G, ushort* Lw, int JK2, int t){
    for (int idx = t; idx < JK2; idx += 512){
        int f = idx*2;
        int j = f / K, k = f - j*K;
        float2 x = *(const float2*)(G + f);
        *(uint*)(Lw + j*Kp + k) = cvt2bf(x.x, x.y);
    }
}

__device__ __forceinline__ bf16x8 afrag_f32(const float* p){
    float4 q0 = *(const float4*)(p), q1 = *(const float4*)(p+4);
    BFU r; r.u[0]=cvt2bf(q0.x,q0.y); r.u[1]=cvt2bf(q0.z,q0.w);
    r.u[2]=cvt2bf(q1.x,q1.y); r.u[3]=cvt2bf(q1.z,q1.w);
    return r.v;
}

#define MFMA16(a,b,c) __builtin_amdgcn_mfma_f32_16x16x32_bf16((a),(b),(c),0,0,0)

__global__ __launch_bounds__(512)
void edge_kernel(const float* __restrict__ edge_s_g, const float* __restrict__ edge_v_g,
                 const int* __restrict__ eidx_g, const float* __restrict__ dist_g,
                 const float* __restrict__ eWv1, const float* __restrict__ eWv2,
                 const float* __restrict__ eWs,  const float* __restrict__ eWg,
                 const float* __restrict__ ebg,  const float* __restrict__ eWd,
                 const float* __restrict__ scaW, const float* __restrict__ scab,
                 const float* __restrict__ e2nW, const float* __restrict__ e2nb,
                 const float* __restrict__ n2eW, const float* __restrict__ n2eb,
                 const float* __restrict__ evnW, const float* __restrict__ evnb,
                 const float* __restrict__ oWv1, const float* __restrict__ oWv2,
                 const float* __restrict__ oWs,  const float* __restrict__ oWg,
                 const float* __restrict__ obg,
                 const float* __restrict__ ns_ws, const float* __restrict__ nv_ws,
                 float* __restrict__ outS, float* __restrict__ outV, int E)
{
    extern __shared__ __align__(16) char Lraw[];
    float*  EA_f   = (float*) (Lraw + X_EA);
    float*  EB_f   = (float*) (Lraw + X_EB);
    float*  ESM_f  = (float*) (Lraw + X_ESM);
    float*  ESM2_f = (float*) (Lraw + X_ESM2);
    ushort* EDD_h  = (ushort*)(Lraw + X_EDD);
    ushort* EEB_h  = (ushort*)(Lraw + X_EEB);
    float*  BIAS_f = (float*) (Lraw + X_BIAS);
    float*  ECUT_f = (float*) (Lraw + X_ECUT);
    int*    EIDX_i = (int*)   (Lraw + X_EIDX);
    ushort* AR_h   = (ushort*)(Lraw + X_AR);
    float*  OS_f   = (float*) (Lraw + X_AR);

    const int t = threadIdx.x;
    const int e = t & 63;
    const int w = __builtin_amdgcn_readfirstlane(t >> 6);
    const size_t e0 = (size_t)blockIdx.x * 64;
    const int valid = (int)min((size_t)64, (size_t)E - e0);
    const float PI_F = 3.14159265358979323846f;

    const int lane = t & 63;
    const int e16  = lane & 15;
    const int kg   = lane >> 4;        // 0..3
    const int mt   = w >> 1;           // 0..3
    const int eA   = mt*16 + e16;      // mfma A row
    const int eD   = mt*16 + kg*4;     // mfma D row base

    // ---- stage 0: inputs + biases + phase-1 weights
    {
        int eL = t>>3, q = t&7;
        size_t row = e0 + (size_t)eL; if (row >= (size_t)E) row = (size_t)E-1;
        const float4* gv = (const float4*)(edge_v_g + row*96);
        float4* av = (float4*)(EA_f + eL*96);
        int e7 = eL&7;
#pragma unroll
        for (int m=0;m<3;m++) av[(q+8*m)^e7] = gv[q+8*m];
        const float* gs = edge_s_g + row*64 + q*8;
        float4 s0 = *(const float4*)(gs), s1 = *(const float4*)(gs+4);
        BFU r; r.u[0]=cvt2bf(s0.x,s0.y); r.u[1]=cvt2bf(s0.z,s0.w);
        r.u[2]=cvt2bf(s1.x,s1.y); r.u[3]=cvt2bf(s1.z,s1.w);
        *(bf16x8*)(EEB_h + eL*136 + 32 + q*8) = r.v;
    }
    if (t < 64) {
        size_t row = e0 + (size_t)t; if (row >= (size_t)E) row = (size_t)E-1;
        EIDX_i[t] = eidx_g[row];
        float dd = dist_g[row];
        float c = 0.5f*(cosf(dd * (PI_F/10.0f)) + 1.0f);
        c = (dd >= 0.0f && dd <= 10.0f) ? c : 0.0f;
        ECUT_f[t] = c;
    } else if (t < 320) {
        int b = t - 64; float v;
        if (b < 32) v = ebg[b];
        else if (b < 160) v = scab[b-32];
        else if (b < 192) v = e2nb[b-160];
        else if (b < 224) v = n2eb[b-192];
        else v = obg[b-224];
        BIAS_f[b] = v;
    }
    stageW<96,104>(eWs,  AR_h + AW_EWS, 3072, t);
    stageW<64,72> (eWg,  AR_h + AW_EWG, 1024, t);
    stageW<64,72> (e2nW, AR_h + AW_E2N, 1024, t);
    stageW<128,136>(n2eW,AR_h + AW_N2E, 2048, t);
    stageW<64,72> (scaW, AR_h + AW_SCA, 4096, t);
    __syncthreads();

    // ---- G1: vi = eWv1 @ v  (EA in place)
    {
        float a[4][3];
        vgemm32s(EA_f + e*96, e&7, eWv1 + (w*4)*32, a);
        __syncthreads();
        store_pack12_swz(EA_f + e*96, e&7, w, a);
    }
    __syncthreads();

    // ---- norm -> EEB cols 0..31 (bf16)
    for (int idx=t; idx<2048; idx+=512){
        int ee=idx>>5, h=idx&31;
        const float* rb = EA_f + ee*96; int e7=ee&7;
        float x0=ld_swz(rb,e7,3*h), x1=ld_swz(rb,e7,3*h+1), x2=ld_swz(rb,e7,3*h+2);
        EEB_h[ee*136 + h] = f2bf(sqrtf(x0*x0+x1*x1+x2*x2));
    }
    __syncthreads();

    // ---- G2 (mfma): es = eWs @ cat (K=96) -> EDD bf16
    {
        const int nt0 = (w & 1) * 2;
        f32x4 acc0 = {0,0,0,0}, acc1 = {0,0,0,0};
        const ushort* Wa = AR_h + AW_EWS;
#pragma unroll
        for (int kt=0; kt<3; kt++){
            int k = kt*32 + kg*8;
            bf16x8 a  = *(const bf16x8*)(EEB_h + eA*136 + k);
            bf16x8 b0 = *(const bf16x8*)(Wa + (nt0*16 + e16)*104 + k);
            bf16x8 b1 = *(const bf16x8*)(Wa + ((nt0+1)*16 + e16)*104 + k);
            acc0 = MFMA16(a, b0, acc0);
            acc1 = MFMA16(a, b1, acc1);
        }
#pragma unroll
        for (int r=0;r<4;r++){
            EDD_h[(eD+r)*72 + nt0*16 + e16]     = f2bf(acc0[r]);
            EDD_h[(eD+r)*72 + (nt0+1)*16 + e16] = f2bf(acc1[r]);
        }
    }
    __syncthreads();

    // ---- G3 (mfma): gate = sigmoid(eWg @ es + ebg) -> ESM f32
    {
        const int j = (w & 1)*16 + e16;
        f32x4 acc = {0,0,0,0};
        const ushort* Wa = AR_h + AW_EWG;
#pragma unroll
        for (int kt=0;kt<2;kt++){
            int k = kt*32 + kg*8;
            bf16x8 a = *(const bf16x8*)(EDD_h + eA*72 + k);
            bf16x8 b = *(const bf16x8*)(Wa + j*72 + k);
            acc = MFMA16(a,b,acc);
        }
        float bg = BIAS_f[j];
#pragma unroll
        for (int r=0;r<4;r++)
            ESM_f[(eD+r)*36 + j] = sigmoidf_(acc[r] + bg);
    }
    __syncthreads();

    // ---- G4: ev = gate * (eWv2 @ vi) -> EB
    {
        float a[4][3];
        vgemm32s(EA_f + e*96, e&7, eWv2 + (w*4)*32, a);
#pragma unroll
        for (int j=0;j<4;j++){
            float g = ESM_f[e*36 + w*4 + j];
            a[j][0]*=g; a[j][1]*=g; a[j][2]*=g;
        }
        store_pack12_swz(EB_f + e*96, e&7, w, a);
    }
    __syncthreads();

    // ---- G5: d = eWd @ ev -> EEB bf16 cols 0..95 (cat dead)
    {
        float a[4][3];
        vgemm32s(EB_f + e*96, e&7, eWd + (w*4)*32, a);
        uint u0=cvt2bf(a[0][0],a[0][1]), u1=cvt2bf(a[0][2],a[1][0]);
        uint u2=cvt2bf(a[1][1],a[1][2]), u3=cvt2bf(a[2][0],a[2][1]);
        uint u4=cvt2bf(a[2][2],a[3][0]), u5=cvt2bf(a[3][1],a[3][2]);
        uint2* dp = (uint2*)(EEB_h + e*136 + w*12);
        dp[0]=make_uint2(u0,u1); dp[1]=make_uint2(u2,u3); dp[2]=make_uint2(u4,u5);
    }
    __syncthreads();

    // ---- VNLeakyReLU on ev (EB in place), leaky on es (EDD in place)
    for (int idx=t; idx<2048; idx+=512){
        int ee=idx>>5, o=idx&31;
        float* rb = EB_f + ee*96; int e7=ee&7;
        float x0=ld_swz(rb,e7,3*o), x1=ld_swz(rb,e7,3*o+1), x2=ld_swz(rb,e7,3*o+2);
        const ushort* dps = EEB_h + ee*136 + 3*o;
        float d0=bf2f(dps[0]), d1=bf2f(dps[1]), d2=bf2f(dps[2]);
        float dot=x0*d0+x1*d1+x2*d2;
        float dn =d0*d0+d1*d1+d2*d2;
        float s_ = dot/(dn + 1e-6f);
        float y0,y1,y2;
        if (dot >= 0.f){ y0=x0; y1=x1; y2=x2; }
        else { y0=x0-s_*d0; y1=x1-s_*d1; y2=x2-s_*d2; }
        st_swz(rb,e7,3*o,   0.01f*x0+0.99f*y0);
        st_swz(rb,e7,3*o+1, 0.01f*x1+0.99f*y1);
        st_swz(rb,e7,3*o+2, 0.01f*x2+0.99f*y2);
    }
    for (int idx=t; idx<4096; idx+=512){
        int ee=idx>>6, k=idx&63;
        ushort* p = EDD_h + ee*72 + k;
        float x = bf2f(*p);
        *p = f2bf(x>=0.f ? x : 0.01f*x);
    }
    __syncthreads();

    // ---- G6: ev_lin = evnW @ ev + evnb -> EA
    {
        float a[4][3];
        vgemm32s(EB_f + e*96, e&7, evnW + (w*4)*32, a);
#pragma unroll
        for (int j=0;j<4;j++){
            float b = evnb[w*4+j];
            a[j][0]+=b; a[j][1]+=b; a[j][2]+=b;
        }
        store_pack12_swz(EA_f + e*96, e&7, w, a);
    }
    __syncthreads();

    // ---- gather: ns_g -> EEB bf16 cols 0..127 (d dead), nv_g -> EB (ev dead)
    {
        int eL = t>>3, q = t&7;
        size_t jn = (size_t)EIDX_i[eL];
        const float4* np_ = (const float4*)(ns_ws + jn*128);
#pragma unroll
        for (int h=0;h<2;h++){
            int k = q*16 + h*8;
            float4 v0 = np_[k/4], v1 = np_[k/4+1];
            BFU r; r.u[0]=cvt2bf(v0.x,v0.y); r.u[1]=cvt2bf(v0.z,v0.w);
            r.u[2]=cvt2bf(v1.x,v1.y); r.u[3]=cvt2bf(v1.z,v1.w);
            *(bf16x8*)(EEB_h + eL*136 + k) = r.v;
        }
        const float4* vp_ = (const float4*)(nv_ws + jn*96);
        float4* db = (float4*)(EB_f + eL*96);
        int e7 = eL&7;
#pragma unroll
        for (int m=0;m<3;m++) db[(q+8*m)^e7] = vp_[q+8*m];
    }
    __syncthreads();

    // ---- G8+G9 (mfma): e2n -> ESM (gate dead), n2e -> ESM2
    {
        const int j = (w & 1)*16 + e16;
        f32x4 acc = {0,0,0,0};
        const ushort* Wa = AR_h + AW_E2N;
#pragma unroll
        for (int kt=0;kt<2;kt++){
            int k = kt*32 + kg*8;
            bf16x8 a = *(const bf16x8*)(EDD_h + eA*72 + k);
            bf16x8 b = *(const bf16x8*)(Wa + j*72 + k);
            acc = MFMA16(a,b,acc);
        }
        f32x4 acc2 = {0,0,0,0};
        const ushort* Wb2 = AR_h + AW_N2E;
#pragma unroll
        for (int kt=0;kt<4;kt++){
            int k = kt*32 + kg*8;
            bf16x8 a = *(const bf16x8*)(EEB_h + eA*136 + k);
            bf16x8 b = *(const bf16x8*)(Wb2 + j*136 + k);
            acc2 = MFMA16(a,b,acc2);
        }
        float b1 = BIAS_f[160 + j], b2 = BIAS_f[192 + j];
#pragma unroll
        for (int r=0;r<4;r++){
            ESM_f[(eD+r)*36 + j]  = acc[r]  + b1;
            ESM2_f[(eD+r)*36 + j] = acc2[r] + b2;
        }
    }
    __syncthreads();

    // ---- y_v = e2n*nv_g + n2e*ev_lin -> EB in place
    for (int idx=t; idx<2048; idx+=512){
        int ee=idx>>5, o=idx&31;
        float g1=ESM_f[ee*36+o], g2=ESM2_f[ee*36+o];
        float* rb = EB_f + ee*96; const float* ra = EA_f + ee*96; int e7=ee&7;
#pragma unroll
        for (int c=0;c<3;c++){
            int d = 3*o+c;
            st_swz(rb,e7,d, g1*ld_swz(rb,e7,d) + g2*ld_swz(ra,e7,d));
        }
    }
    __syncthreads();

    // ---- G7 (mfma): y_s = ns_g * (scaW @ ses + scab) -> EEB bf16 in place
    {
        const int nt0 = (w & 1) * 4;
        f32x4 acc[4] = {{0,0,0,0},{0,0,0,0},{0,0,0,0},{0,0,0,0}};
        const ushort* Wa = AR_h + AW_SCA;
#pragma unroll
        for (int kt=0;kt<2;kt++){
            int k = kt*32 + kg*8;
            bf16x8 a = *(const bf16x8*)(EDD_h + eA*72 + k);
#pragma unroll
            for (int n=0;n<4;n++){
                bf16x8 b = *(const bf16x8*)(Wa + ((nt0+n)*16 + e16)*72 + k);
                acc[n] = MFMA16(a,b,acc[n]);
            }
        }
#pragma unroll
        for (int n=0;n<4;n++){
            int j = (nt0+n)*16 + e16;
            float sb = BIAS_f[32 + j];
#pragma unroll
            for (int r=0;r<4;r++){
                ushort* slot = EEB_h + (eD+r)*136 + j;
                float ns = bf2f(*slot);
                *slot = f2bf(ns * (acc[n][r] + sb));
            }
        }
    }
    __syncthreads();

    // ---- phase-2 weight staging (sca/n2e/e2n/eWs/eWg all dead)
    stageW<160,168>(oWs, AR_h + AW_OWS, 10240, t);
    stageW<128,136>(oWg, AR_h + AW_OWG,  2048, t);

    // ---- G10: vi_o = oWv1 @ y_v -> EA
    {
        float a[4][3];
        vgemm32s(EB_f + e*96, e&7, oWv1 + (w*4)*32, a);
        __syncthreads();
        store_pack12_swz(EA_f + e*96, e&7, w, a);
    }
    __syncthreads();

    // ---- norm_o -> ESM f32 (e2n dead)
    for (int idx=t; idx<2048; idx+=512){
        int ee=idx>>5, h=idx&31;
        const float* rb = EA_f + ee*96; int e7=ee&7;
        float x0=ld_swz(rb,e7,3*h), x1=ld_swz(rb,e7,3*h+1), x2=ld_swz(rb,e7,3*h+2);
        ESM_f[ee*36+h] = sqrtf(x0*x0+x1*x1+x2*x2);
    }
    __syncthreads();

    // ---- G13: ov_pre = oWv2 @ vi_o -> EB (y_v dead)
    {
        float a[4][3];
        vgemm32s(EA_f + e*96, e&7, oWv2 + (w*4)*32, a);
        store_pack12_swz(EB_f + e*96, e&7, w, a);
    }
    __syncthreads();

    // ---- G11 (mfma): os = oWs @ [norm_o(32) ; y_s(128)] -> OS f32 (over oWs)
    {
        const int nt0 = (w & 1) * 4;
        f32x4 acc[4] = {{0,0,0,0},{0,0,0,0},{0,0,0,0},{0,0,0,0}};
        const ushort* Wa = AR_h + AW_OWS;
        {
            int k = kg*8;
            bf16x8 a = afrag_f32(ESM_f + eA*36 + k);
#pragma unroll
            for (int n=0;n<4;n++){
                bf16x8 b = *(const bf16x8*)(Wa + ((nt0+n)*16+e16)*168 + k);
                acc[n] = MFMA16(a,b,acc[n]);
            }
        }
#pragma unroll
        for (int kt=1;kt<5;kt++){
            int k = kt*32 + kg*8;
            bf16x8 a = *(const bf16x8*)(EEB_h + eA*136 + (k-32));
#pragma unroll
            for (int n=0;n<4;n++){
                bf16x8 b = *(const bf16x8*)(Wa + ((nt0+n)*16+e16)*168 + k);
                acc[n] = MFMA16(a,b,acc[n]);
            }
        }
        __syncthreads();   // all oWs reads done before overwrite
#pragma unroll
        for (int n=0;n<4;n++){
            int j = (nt0+n)*16 + e16;
#pragma unroll
            for (int r=0;r<4;r++){
                int ee = eD+r;
                OS_f[ee*128 + (((j>>2)^(ee&7))<<2) + (j&3)] = acc[n][r];
            }
        }
    }
    __syncthreads();

    // ---- G12 (mfma): gate_o = sigmoid(oWg @ os + obg) -> ESM2
    {
        const int j = (w & 1)*16 + e16;
        f32x4 acc = {0,0,0,0};
        const ushort* Wa = AR_h + AW_OWG;
        const float* rp = OS_f + eA*128;
        int e7a = eA & 7;
#pragma unroll
        for (int kt=0;kt<4;kt++){
            int k = kt*32 + kg*8;
            int q = k >> 2;
            float4 x0 = *(const float4*)(rp + ((q^e7a)<<2));
            float4 x1 = *(const float4*)(rp + (((q+1)^e7a)<<2));
            BFU af; af.u[0]=cvt2bf(x0.x,x0.y); af.u[1]=cvt2bf(x0.z,x0.w);
            af.u[2]=cvt2bf(x1.x,x1.y); af.u[3]=cvt2bf(x1.z,x1.w);
            bf16x8 b = *(const bf16x8*)(Wa + j*136 + k);
            acc = MFMA16(af.v, b, acc);
        }
        float ob = BIAS_f[224 + j];
#pragma unroll
        for (int r=0;r<4;r++)
            ESM2_f[(eD+r)*36 + j] = sigmoidf_(acc[r] + ob);
    }
    __syncthreads();

    // ---- outputs with cutoff
    if (e < valid) {
        float c = ECUT_f[e];
        int e7 = e&7;
        const float* rp = OS_f + e*128;
        float4* po = (float4*)(outS + (e0+(size_t)e)*128 + w*16);
#pragma unroll
        for (int qq=0;qq<4;qq++){
            float4 v = *(const float4*)(rp + (((w*4+qq)^e7)<<2));
            po[qq] = make_float4(v.x*c, v.y*c, v.z*c, v.w*c);
        }
        float g0 = ESM2_f[e*36 + w*4 + 0]*c;
        float g1 = ESM2_f[e*36 + w*4 + 1]*c;
        float g2 = ESM2_f[e*36 + w*4 + 2]*c;
        float g3 = ESM2_f[e*36 + w*4 + 3]*c;
        const float4* pb = (const float4*)(EB_f + e*96);
        float4 v0 = pb[(3*w+0)^e7], v1 = pb[(3*w+1)^e7], v2 = pb[(3*w+2)^e7];
        float4* pv = (float4*)(outV + (e0+(size_t)e)*96 + w*12);
        pv[0] = make_float4(v0.x*g0, v0.y*g0, v0.z*g0, v0.w*g1);
        pv[1] = make_float4(v1.x*g1, v1.y*g1, v1.z*g2, v1.w*g2);
        pv[2] = make_float4(v2.x*g2, v2.y*g3, v2.z*g3, v2.w*g3);
    }
}

// =====================================================================
extern "C" void kernel_launch(void* const* d_in, const int* in_sizes, int n_in,
                              void* d_out, int out_size, void* d_ws, size_t ws_size,
                              hipStream_t stream) {
    const float* node_s = (const float*)d_in[0];
    const float* node_v = (const float*)d_in[1];
    const float* edge_s = (const float*)d_in[2];
    const float* edge_v = (const float*)d_in[3];
    const int*   eidx   = (const int*)d_in[4];
    const float* dist   = (const float*)d_in[5];
    const float* nWv1=(const float*)d_in[6],  *nWv2=(const float*)d_in[7];
    const float* nWs =(const float*)d_in[8],  *nWg =(const float*)d_in[9],  *nbg=(const float*)d_in[10];
    const float* eWv1=(const float*)d_in[11], *eWv2=(const float*)d_in[12];
    const float* eWs =(const float*)d_in[13], *eWg =(const float*)d_in[14], *ebg=(const float*)d_in[15];
    const float* eWd =(const float*)d_in[16];
    const float* scaW=(const float*)d_in[17], *scab=(const float*)d_in[18];
    const float* e2nW=(const float*)d_in[19], *e2nb=(const float*)d_in[20];
    const float* n2eW=(const float*)d_in[21], *n2eb=(const float*)d_in[22];
    const float* evnW=(const float*)d_in[23], *evnb=(const float*)d_in[24];
    const float* oWv1=(const float*)d_in[25], *oWv2=(const float*)d_in[26];
    const float* oWs =(const float*)d_in[27], *oWg =(const float*)d_in[28], *obg=(const float*)d_in[29];

    const int N = in_sizes[0] / 128;
    const int E = in_sizes[2] / 64;

    float* ns_ws = (float*)d_ws;
    float* nv_ws = ns_ws + (size_t)N*128;
    float* outS  = (float*)d_out;
    float* outV  = outS + (size_t)E*128;

    hipFuncSetAttribute((const void*)node_kernel, hipFuncAttributeMaxDynamicSharedMemorySize, NODE_LDS_BYTES);
    hipFuncSetAttribute((const void*)edge_kernel, hipFuncAttributeMaxDynamicSharedMemorySize, EDGE_LDS_BYTES);

    const int nb = (N + 63) / 64;
    node_kernel<<<nb, 512, NODE_LDS_BYTES, stream>>>(node_s, node_v, nWv1, nWv2, nWs, nWg, nbg,
                                                     ns_ws, nv_ws, N);

    const int eb = (E + 63) / 64;
    edge_kernel<<<eb, 512, EDGE_LDS_BYTES, stream>>>(edge_s, edge_v, eidx, dist,
                                                     eWv1, eWv2, eWs, eWg, ebg, eWd,
                                                     scaW, scab, e2nW, e2nb, n2eW, n2eb, evnW, evnb,
                                                     oWv1, oWv2, oWs, oWg, obg,
                                                     ns_ws, nv_ws, outS, outV, E);
}